// Round 1
// baseline (391.612 us; speedup 1.0000x reference)
//
#include <hip/hip_runtime.h>
#include <math.h>

#define H 8192
#define NSPLIT 64
#define ROWS_PER_SPLIT (H / NSPLIT)   // 128
#define JCHUNK 1024                   // 256 threads * float4

// ws layout (floats):
//   h1      : [0, H)
//   h2      : [H, 2H)
//   partial : [2H, 2H + NSPLIT*H)    -> total ~2.2 MB

// ---------------- k1: h1 = relu(state @ W1 + b1) ----------------
__global__ void k1_h1(const float* __restrict__ state,
                      const float* __restrict__ W1,
                      const float* __restrict__ b1,
                      float* __restrict__ h1) {
    int j = (blockIdx.x * blockDim.x + threadIdx.x) * 4;   // column
    float4 acc = *(const float4*)(b1 + j);
    #pragma unroll 6
    for (int i = 0; i < 42; ++i) {
        float s = state[i];                                 // uniform scalar load
        float4 w = *(const float4*)(W1 + (size_t)i * H + j);
        acc.x = fmaf(s, w.x, acc.x);
        acc.y = fmaf(s, w.y, acc.y);
        acc.z = fmaf(s, w.z, acc.z);
        acc.w = fmaf(s, w.w, acc.w);
    }
    acc.x = fmaxf(acc.x, 0.0f);
    acc.y = fmaxf(acc.y, 0.0f);
    acc.z = fmaxf(acc.z, 0.0f);
    acc.w = fmaxf(acc.w, 0.0f);
    *(float4*)(h1 + j) = acc;
}

// ---------------- k2: split-K GEMV over W2 -> partials ----------------
__global__ void k2_partial(const float* __restrict__ W2,
                           const float* __restrict__ h1,
                           float* __restrict__ partial) {
    int j  = blockIdx.x * JCHUNK + threadIdx.x * 4;  // column (float4)
    int i0 = blockIdx.y * ROWS_PER_SPLIT;            // row slice start
    float4 acc = make_float4(0.f, 0.f, 0.f, 0.f);
    const float* wp = W2 + (size_t)i0 * H + j;
    const float* hp = h1 + i0;
    #pragma unroll 16
    for (int ii = 0; ii < ROWS_PER_SPLIT; ++ii) {
        float s  = hp[ii];                           // uniform scalar load
        float4 w = *(const float4*)wp;
        wp += H;
        acc.x = fmaf(s, w.x, acc.x);
        acc.y = fmaf(s, w.y, acc.y);
        acc.z = fmaf(s, w.z, acc.z);
        acc.w = fmaf(s, w.w, acc.w);
    }
    *(float4*)(partial + (size_t)blockIdx.y * H + j) = acc;
}

// ---------------- k3: reduce partials + b2 + relu -> h2 ----------------
__global__ void k3_reduce(const float* __restrict__ partial,
                          const float* __restrict__ b2,
                          float* __restrict__ h2) {
    int j = blockIdx.x * blockDim.x + threadIdx.x;   // scalar column
    float acc = b2[j];
    #pragma unroll 8
    for (int s = 0; s < NSPLIT; ++s) {
        acc += partial[(size_t)s * H + j];
    }
    h2[j] = fmaxf(acc, 0.0f);
}

// ---------------- k4: pen = h2 @ W3 + b3; value + masked softmax ----------------
__global__ void k4_final(const float* __restrict__ h2,
                         const float* __restrict__ W3,
                         const float* __restrict__ b3,
                         const float* __restrict__ state,
                         float* __restrict__ out) {
    // single block, 1024 threads (16 waves)
    float acc[8];
    #pragma unroll
    for (int k = 0; k < 8; ++k) acc[k] = 0.0f;

    #pragma unroll
    for (int r = 0; r < H / 1024; ++r) {             // 8 rows per thread
        int j = threadIdx.x + r * 1024;
        float h = h2[j];
        float4 w0 = *(const float4*)(W3 + (size_t)j * 8);
        float4 w1 = *(const float4*)(W3 + (size_t)j * 8 + 4);
        acc[0] = fmaf(h, w0.x, acc[0]);
        acc[1] = fmaf(h, w0.y, acc[1]);
        acc[2] = fmaf(h, w0.z, acc[2]);
        acc[3] = fmaf(h, w0.w, acc[3]);
        acc[4] = fmaf(h, w1.x, acc[4]);
        acc[5] = fmaf(h, w1.y, acc[5]);
        acc[6] = fmaf(h, w1.z, acc[6]);
        acc[7] = fmaf(h, w1.w, acc[7]);
    }

    // wave-level shuffle reduction (64 lanes)
    #pragma unroll
    for (int off = 32; off > 0; off >>= 1) {
        #pragma unroll
        for (int k = 0; k < 8; ++k)
            acc[k] += __shfl_down(acc[k], off);
    }

    __shared__ float red[16][8];
    int wave = threadIdx.x >> 6;
    int lane = threadIdx.x & 63;
    if (lane == 0) {
        #pragma unroll
        for (int k = 0; k < 8; ++k) red[wave][k] = acc[k];
    }
    __syncthreads();

    if (threadIdx.x == 0) {
        float pen[8];
        #pragma unroll
        for (int k = 0; k < 8; ++k) {
            float s = b3[k];
            for (int w = 0; w < 16; ++w) s += red[w][k];
            pen[k] = s;
        }
        // value = pen[7]
        out[0] = pen[7];
        // masked softmax over pen[0..6] where state[i] == 0
        bool legal[7];
        float m = -INFINITY;
        for (int i = 0; i < 7; ++i) {
            legal[i] = (state[i] == 0.0f);
            if (legal[i] && pen[i] > m) m = pen[i];
        }
        float e[7];
        float sum = 0.0f;
        for (int i = 0; i < 7; ++i) {
            e[i] = legal[i] ? expf(pen[i] - m) : 0.0f;
            sum += e[i];
        }
        float inv = 1.0f / sum;
        for (int i = 0; i < 7; ++i) out[1 + i] = e[i] * inv;
    }
}

extern "C" void kernel_launch(void* const* d_in, const int* in_sizes, int n_in,
                              void* d_out, int out_size, void* d_ws, size_t ws_size,
                              hipStream_t stream) {
    const float* state = (const float*)d_in[0];
    const float* W1    = (const float*)d_in[1];
    const float* b1    = (const float*)d_in[2];
    const float* W2    = (const float*)d_in[3];
    const float* b2    = (const float*)d_in[4];
    const float* W3    = (const float*)d_in[5];
    const float* b3    = (const float*)d_in[6];
    float* out = (float*)d_out;

    float* ws      = (float*)d_ws;
    float* h1      = ws;
    float* h2      = ws + H;
    float* partial = ws + 2 * H;

    // k1: 8192 cols / (256 thr * 4) = 8 blocks
    hipLaunchKernelGGL(k1_h1, dim3(H / 1024), dim3(256), 0, stream, state, W1, b1, h1);
    // k2: (8 col-chunks) x (64 K-splits) = 512 blocks
    hipLaunchKernelGGL(k2_partial, dim3(H / JCHUNK, NSPLIT), dim3(256), 0, stream, W2, h1, partial);
    // k3: 8192 / 256 = 32 blocks
    hipLaunchKernelGGL(k3_reduce, dim3(H / 256), dim3(256), 0, stream, partial, b2, h2);
    // k4: single block
    hipLaunchKernelGGL(k4_final, dim3(1), dim3(1024), 0, stream, h2, W3, b3, state, out);
}

// Round 2
// 364.835 us; speedup vs baseline: 1.0734x; 1.0734x over previous
//
#include <hip/hip_runtime.h>
#include <math.h>

#define H 8192
#define NSPLIT 64
#define NSEG 8          // k1 blocks / compaction segments
#define SEGCOLS 1024    // columns per segment

// ws layout (float index):
//   vals    : [0, 8192)            compacted h1 values
//   rows    : [8192, 16384)        compacted h1 row indices (int)
//   cnt     : [16384, 16392)       per-segment counts (int)
//   pen     : [16392, 16400)       h2 @ W3 accumulator (8 floats)
//   partial : [16400, 16400+NSPLIT*H)
#define WS_VALS 0
#define WS_ROWS 8192
#define WS_CNT 16384
#define WS_PEN 16392
#define WS_PARTIAL 16400

// ---- k1: h1 = relu(state@W1 + b1); compact nonzeros per segment; zero pen ----
__global__ void k1_h1(const float* __restrict__ state,
                      const float* __restrict__ W1,
                      const float* __restrict__ b1,
                      float* __restrict__ vals,
                      int* __restrict__ rows,
                      int* __restrict__ cnt,
                      float* __restrict__ pen) {
    __shared__ float sv[SEGCOLS];
    __shared__ int   sr[SEGCOLS];
    __shared__ int   scnt;
    int tid = threadIdx.x;
    if (tid == 0) scnt = 0;
    if (blockIdx.x == 0 && tid < 8) pen[tid] = 0.0f;   // zero pen for k3's atomics
    __syncthreads();

    int j = blockIdx.x * SEGCOLS + tid * 4;
    float4 acc = *(const float4*)(b1 + j);
    #pragma unroll 6
    for (int i = 0; i < 42; ++i) {
        float s = state[i];
        float4 w = *(const float4*)(W1 + (size_t)i * H + j);
        acc.x = fmaf(s, w.x, acc.x);
        acc.y = fmaf(s, w.y, acc.y);
        acc.z = fmaf(s, w.z, acc.z);
        acc.w = fmaf(s, w.w, acc.w);
    }
    float v[4] = { fmaxf(acc.x, 0.f), fmaxf(acc.y, 0.f),
                   fmaxf(acc.z, 0.f), fmaxf(acc.w, 0.f) };
    #pragma unroll
    for (int c = 0; c < 4; ++c) {
        if (v[c] > 0.0f) {
            int p = atomicAdd(&scnt, 1);   // LDS atomic
            sv[p] = v[c];
            sr[p] = j + c;
        }
    }
    __syncthreads();
    int n = scnt;
    if (tid == 0) cnt[blockIdx.x] = n;
    int base = blockIdx.x * SEGCOLS;
    for (int p = tid; p < n; p += blockDim.x) {
        vals[base + p] = sv[p];
        rows[base + p] = sr[p];
    }
}

// ---- k2: sparse split-K GEMV over W2 (only nonzero h1 rows) -> partials ----
__global__ void k2_partial(const float* __restrict__ W2,
                           const float* __restrict__ vals,
                           const int* __restrict__ rows,
                           const int* __restrict__ cnt,
                           float* __restrict__ partial) {
    int j = blockIdx.x * SEGCOLS + threadIdx.x * 4;   // column (float4)

    // prefix of the 8 segment counts (uniform scalar work)
    int c[NSEG], pre[NSEG + 1];
    pre[0] = 0;
    #pragma unroll
    for (int b = 0; b < NSEG; ++b) { c[b] = cnt[b]; pre[b + 1] = pre[b] + c[b]; }
    int total = pre[NSEG];
    int chunk = (total + NSPLIT - 1) / NSPLIT;
    int glo = blockIdx.y * chunk;
    int ghi = min(glo + chunk, total);

    float4 acc = make_float4(0.f, 0.f, 0.f, 0.f);
    #pragma unroll
    for (int b = 0; b < NSEG; ++b) {
        int lo = max(glo, pre[b]);
        int hi = min(ghi, pre[b] + c[b]);
        int off = b * SEGCOLS - pre[b];   // map global pos -> segment-local slot
        #pragma unroll 4
        for (int p = lo; p < hi; ++p) {
            float s = vals[off + p];
            int   r = rows[off + p];
            float4 w = *(const float4*)(W2 + (size_t)r * H + j);
            acc.x = fmaf(s, w.x, acc.x);
            acc.y = fmaf(s, w.y, acc.y);
            acc.z = fmaf(s, w.z, acc.z);
            acc.w = fmaf(s, w.w, acc.w);
        }
    }
    *(float4*)(partial + (size_t)blockIdx.y * H + j) = acc;
}

// ---- k3: h2 = relu(sum partials + b2); pen += h2 @ W3 (atomic) ----
__global__ void k3_reduce(const float* __restrict__ partial,
                          const float* __restrict__ b2,
                          const float* __restrict__ W3,
                          float* __restrict__ pen) {
    int j = blockIdx.x * blockDim.x + threadIdx.x;   // one column per thread
    float acc = b2[j];
    #pragma unroll 8
    for (int s = 0; s < NSPLIT; ++s) acc += partial[(size_t)s * H + j];
    float h = fmaxf(acc, 0.0f);

    float4 w0 = *(const float4*)(W3 + (size_t)j * 8);
    float4 w1 = *(const float4*)(W3 + (size_t)j * 8 + 4);
    float a[8] = { h * w0.x, h * w0.y, h * w0.z, h * w0.w,
                   h * w1.x, h * w1.y, h * w1.z, h * w1.w };

    #pragma unroll
    for (int off = 32; off > 0; off >>= 1) {
        #pragma unroll
        for (int k = 0; k < 8; ++k) a[k] += __shfl_down(a[k], off);
    }
    if ((threadIdx.x & 63) == 0) {
        #pragma unroll
        for (int k = 0; k < 8; ++k) atomicAdd(&pen[k], a[k]);
    }
}

// ---- k4: value + masked softmax from pen ----
__global__ void k4_final(const float* __restrict__ pen,
                         const float* __restrict__ b3,
                         const float* __restrict__ state,
                         float* __restrict__ out) {
    if (threadIdx.x == 0) {
        float p8[8];
        #pragma unroll
        for (int k = 0; k < 8; ++k) p8[k] = pen[k] + b3[k];
        out[0] = p8[7];                       // value
        bool legal[7];
        float m = -INFINITY;
        for (int i = 0; i < 7; ++i) {
            legal[i] = (state[i] == 0.0f);
            if (legal[i] && p8[i] > m) m = p8[i];
        }
        float e[7], sum = 0.0f;
        for (int i = 0; i < 7; ++i) {
            e[i] = legal[i] ? expf(p8[i] - m) : 0.0f;
            sum += e[i];
        }
        float inv = 1.0f / sum;
        for (int i = 0; i < 7; ++i) out[1 + i] = e[i] * inv;
    }
}

extern "C" void kernel_launch(void* const* d_in, const int* in_sizes, int n_in,
                              void* d_out, int out_size, void* d_ws, size_t ws_size,
                              hipStream_t stream) {
    const float* state = (const float*)d_in[0];
    const float* W1    = (const float*)d_in[1];
    const float* b1    = (const float*)d_in[2];
    const float* W2    = (const float*)d_in[3];
    const float* b2    = (const float*)d_in[4];
    const float* W3    = (const float*)d_in[5];
    const float* b3    = (const float*)d_in[6];
    float* out = (float*)d_out;

    float* ws      = (float*)d_ws;
    float* vals    = ws + WS_VALS;
    int*   rows    = (int*)(ws + WS_ROWS);
    int*   cnt     = (int*)(ws + WS_CNT);
    float* pen     = ws + WS_PEN;
    float* partial = ws + WS_PARTIAL;

    hipLaunchKernelGGL(k1_h1, dim3(NSEG), dim3(256), 0, stream,
                       state, W1, b1, vals, rows, cnt, pen);
    hipLaunchKernelGGL(k2_partial, dim3(H / SEGCOLS, NSPLIT), dim3(256), 0, stream,
                       W2, vals, rows, cnt, partial);
    hipLaunchKernelGGL(k3_reduce, dim3(H / 256), dim3(256), 0, stream,
                       partial, b2, W3, pen);
    hipLaunchKernelGGL(k4_final, dim3(1), dim3(64), 0, stream,
                       pen, b3, state, out);
}

// Round 4
// 350.366 us; speedup vs baseline: 1.1177x; 1.0413x over previous
//
#include <hip/hip_runtime.h>
#include <math.h>

#define H 8192
#define NSPLIT 64
#define NSEG 8          // k1 blocks / compaction segments
#define SEGCOLS 1024    // columns per segment

typedef float floatx4 __attribute__((ext_vector_type(4)));   // native vector for nt builtins

// ws layout (float index):
//   vals    : [0, 8192)            compacted h1 values
//   rows    : [8192, 16384)        compacted h1 row indices (int)
//   cnt     : [16384, 16392)       per-segment counts (int)
//   pen     : [16392, 16400)       h2 @ W3 accumulator (8 floats)
//   partial : [16400, 16400+NSPLIT*H)
#define WS_VALS 0
#define WS_ROWS 8192
#define WS_CNT 16384
#define WS_PEN 16392
#define WS_PARTIAL 16400

// ---- k1: h1 = relu(state@W1 + b1); compact nonzeros per segment; zero pen ----
__global__ void k1_h1(const float* __restrict__ state,
                      const float* __restrict__ W1,
                      const float* __restrict__ b1,
                      float* __restrict__ vals,
                      int* __restrict__ rows,
                      int* __restrict__ cnt,
                      float* __restrict__ pen) {
    __shared__ float sv[SEGCOLS];
    __shared__ int   sr[SEGCOLS];
    __shared__ int   scnt;
    int tid = threadIdx.x;
    if (tid == 0) scnt = 0;
    if (blockIdx.x == 0 && tid < 8) pen[tid] = 0.0f;   // zero pen for k3's atomics
    __syncthreads();

    int j = blockIdx.x * SEGCOLS + tid * 4;
    float4 acc = *(const float4*)(b1 + j);
    #pragma unroll 6
    for (int i = 0; i < 42; ++i) {
        float s = state[i];
        float4 w = *(const float4*)(W1 + (size_t)i * H + j);
        acc.x = fmaf(s, w.x, acc.x);
        acc.y = fmaf(s, w.y, acc.y);
        acc.z = fmaf(s, w.z, acc.z);
        acc.w = fmaf(s, w.w, acc.w);
    }
    float v[4] = { fmaxf(acc.x, 0.f), fmaxf(acc.y, 0.f),
                   fmaxf(acc.z, 0.f), fmaxf(acc.w, 0.f) };
    #pragma unroll
    for (int c = 0; c < 4; ++c) {
        if (v[c] > 0.0f) {
            int p = atomicAdd(&scnt, 1);   // LDS atomic
            sv[p] = v[c];
            sr[p] = j + c;
        }
    }
    __syncthreads();
    int n = scnt;
    if (tid == 0) cnt[blockIdx.x] = n;
    int base = blockIdx.x * SEGCOLS;
    for (int p = tid; p < n; p += blockDim.x) {
        vals[base + p] = sv[p];
        rows[base + p] = sr[p];
    }
}

// ---- k2: sparse split-K GEMV over W2 (only nonzero h1 rows) -> partials ----
__global__ __launch_bounds__(256) void k2_partial(
        const float* __restrict__ W2,
        const float* __restrict__ vals,
        const int* __restrict__ rows,
        const int* __restrict__ cnt,
        float* __restrict__ partial) {
    int j = blockIdx.x * SEGCOLS + threadIdx.x * 4;   // column (float4)

    // prefix of the 8 segment counts (uniform scalar work)
    int c[NSEG], pre[NSEG + 1];
    pre[0] = 0;
    #pragma unroll
    for (int b = 0; b < NSEG; ++b) { c[b] = cnt[b]; pre[b + 1] = pre[b] + c[b]; }
    int total = pre[NSEG];
    int chunk = (total + NSPLIT - 1) / NSPLIT;
    int glo = blockIdx.y * chunk;
    int ghi = min(glo + chunk, total);

    float4 acc = make_float4(0.f, 0.f, 0.f, 0.f);
    #pragma unroll
    for (int b = 0; b < NSEG; ++b) {
        int lo = max(glo, pre[b]);
        int hi = min(ghi, pre[b] + c[b]);
        int off = b * SEGCOLS - pre[b];   // map global pos -> segment-local slot
        #pragma unroll 8
        for (int p = lo; p < hi; ++p) {
            float s = vals[off + p];
            int   r = rows[off + p];
            // stream W2 with non-temporal hint: each byte is used exactly once
            const floatx4* wp = (const floatx4*)(W2 + (size_t)r * H + j);
            floatx4 w = __builtin_nontemporal_load(wp);
            acc.x = fmaf(s, w.x, acc.x);
            acc.y = fmaf(s, w.y, acc.y);
            acc.z = fmaf(s, w.z, acc.z);
            acc.w = fmaf(s, w.w, acc.w);
        }
    }
    *(float4*)(partial + (size_t)blockIdx.y * H + j) = acc;
}

// ---- k3: h2 = relu(sum partials + b2); pen += h2 @ W3 (atomic) ----
__global__ void k3_reduce(const float* __restrict__ partial,
                          const float* __restrict__ b2,
                          const float* __restrict__ W3,
                          float* __restrict__ pen) {
    int j = blockIdx.x * blockDim.x + threadIdx.x;   // one column per thread
    float acc = b2[j];
    #pragma unroll 8
    for (int s = 0; s < NSPLIT; ++s)
        acc += __builtin_nontemporal_load(partial + (size_t)s * H + j);
    float h = fmaxf(acc, 0.0f);

    float4 w0 = *(const float4*)(W3 + (size_t)j * 8);
    float4 w1 = *(const float4*)(W3 + (size_t)j * 8 + 4);
    float a[8] = { h * w0.x, h * w0.y, h * w0.z, h * w0.w,
                   h * w1.x, h * w1.y, h * w1.z, h * w1.w };

    #pragma unroll
    for (int off = 32; off > 0; off >>= 1) {
        #pragma unroll
        for (int k = 0; k < 8; ++k) a[k] += __shfl_down(a[k], off);
    }
    if ((threadIdx.x & 63) == 0) {
        #pragma unroll
        for (int k = 0; k < 8; ++k) atomicAdd(&pen[k], a[k]);
    }
}

// ---- k4: value + masked softmax from pen ----
__global__ void k4_final(const float* __restrict__ pen,
                         const float* __restrict__ b3,
                         const float* __restrict__ state,
                         float* __restrict__ out) {
    if (threadIdx.x == 0) {
        float p8[8];
        #pragma unroll
        for (int k = 0; k < 8; ++k) p8[k] = pen[k] + b3[k];
        out[0] = p8[7];                       // value
        bool legal[7];
        float m = -INFINITY;
        for (int i = 0; i < 7; ++i) {
            legal[i] = (state[i] == 0.0f);
            if (legal[i] && p8[i] > m) m = p8[i];
        }
        float e[7], sum = 0.0f;
        for (int i = 0; i < 7; ++i) {
            e[i] = legal[i] ? expf(p8[i] - m) : 0.0f;
            sum += e[i];
        }
        float inv = 1.0f / sum;
        for (int i = 0; i < 7; ++i) out[1 + i] = e[i] * inv;
    }
}

extern "C" void kernel_launch(void* const* d_in, const int* in_sizes, int n_in,
                              void* d_out, int out_size, void* d_ws, size_t ws_size,
                              hipStream_t stream) {
    const float* state = (const float*)d_in[0];
    const float* W1    = (const float*)d_in[1];
    const float* b1    = (const float*)d_in[2];
    const float* W2    = (const float*)d_in[3];
    const float* b2    = (const float*)d_in[4];
    const float* W3    = (const float*)d_in[5];
    const float* b3    = (const float*)d_in[6];
    float* out = (float*)d_out;

    float* ws      = (float*)d_ws;
    float* vals    = ws + WS_VALS;
    int*   rows    = (int*)(ws + WS_ROWS);
    int*   cnt     = (int*)(ws + WS_CNT);
    float* pen     = ws + WS_PEN;
    float* partial = ws + WS_PARTIAL;

    hipLaunchKernelGGL(k1_h1, dim3(NSEG), dim3(256), 0, stream,
                       state, W1, b1, vals, rows, cnt, pen);
    hipLaunchKernelGGL(k2_partial, dim3(H / SEGCOLS, NSPLIT), dim3(256), 0, stream,
                       W2, vals, rows, cnt, partial);
    hipLaunchKernelGGL(k3_reduce, dim3(H / 256), dim3(256), 0, stream,
                       partial, b2, W3, pen);
    hipLaunchKernelGGL(k4_final, dim3(1), dim3(64), 0, stream,
                       pen, b3, state, out);
}